// Round 6
// baseline (1219.041 us; speedup 1.0000x reference)
//
#include <hip/hip_runtime.h>
#include <math.h>

// I-BERT IntSoftmax, exact-numerics replication of the JAX reference.
// x: (1,12,2048,2048) f32; 24576 rows of S=2048.
// R6: R5 persistent-fused kernel at 6 blocks/CU (1536 blocks, launch_bounds(256,6))
//     -> 24 waves/CU latency hiding; s_sleep-throttled spins.
//     R5 measured the win: fused structure does only ~392 MB HBM traffic (L3
//     serves phase-2 re-read); it was latency-bound at 8 waves/CU (15% BW).

#define ROW_S 2048
#define GRID  1536
#define TPB   256

typedef float floatx4 __attribute__((ext_vector_type(4)));

struct Gsync {
    unsigned count;      // arrive counter          (offset 0)
    unsigned flag;       // scalars-ready flag      (offset 4)
    unsigned amax_bits;  // global max|x| as monotone uint bits (amax >= 0)
    unsigned _pad;
    double exp_sf_d;     // exp_sf (f64) — fixedpoint_mul divisor
    double inv_exp_sf;   // RN(1/exp_sf_d)
    double m_int;        // 31-bit mantissa
    double inv_pow;      // 2^(e-31) exact
    float  sf, inv_sf, x0_int, inv_x0, b_int, c_int, thirty_x0, _pad2;
};

// Markstein: with inv = RN(1/b), returns RN(a/b) bit-exactly.
__device__ __forceinline__ float div_rn(float a, float b, float inv) {
    const float q0 = __fmul_rn(a, inv);
    const float r  = __fmaf_rn(-b, q0, a);
    return __fmaf_rn(r, inv, q0);
}
__device__ __forceinline__ double ddiv_rn(double a, double b, double inv) {
    const double q0 = __dmul_rn(a, inv);
    const double r  = __fma_rn(-b, q0, a);
    return __fma_rn(r, inv, q0);
}

__global__ __launch_bounds__(TPB, 6) void k_fused(const float* __restrict__ x,
                                                  float* __restrict__ out,
                                                  Gsync* __restrict__ g,
                                                  int rows) {
    const int tid  = threadIdx.x;
    const int wave = tid >> 6, lane = tid & 63;
    const int rpb   = rows / GRID;     // 16
    const int iters = rpb >> 2;        // 4 row-groups of 4 (one row per wave)
    const int row0  = blockIdx.x * rpb;

    __shared__ float rowmax_s[16];
    __shared__ float amax_s[4];

    const float4* x4 = (const float4*)x;

    // ---------------- phase 1: per-row max + global abs-max ----------------
    float vminall = INFINITY, rmall = -INFINITY;
    for (int k = 0; k < iters; ++k) {
        const int rl = (k << 2) + wave;
        const size_t b4 = (size_t)(row0 + rl) * (ROW_S / 4) + lane;
        float4 v[8];
#pragma unroll
        for (int j = 0; j < 8; ++j) v[j] = x4[b4 + 64 * j];
        float vmax = -INFINITY;
#pragma unroll
        for (int j = 0; j < 8; ++j) {
            vmax    = fmaxf(vmax,    fmaxf(fmaxf(v[j].x, v[j].y), fmaxf(v[j].z, v[j].w)));
            vminall = fminf(vminall, fminf(fminf(v[j].x, v[j].y), fminf(v[j].z, v[j].w)));
        }
#pragma unroll
        for (int m = 32; m > 0; m >>= 1) vmax = fmaxf(vmax, __shfl_xor(vmax, m));
        if (lane == 0) rowmax_s[rl] = vmax;
        rmall = fmaxf(rmall, vmax);
    }
#pragma unroll
    for (int m = 32; m > 0; m >>= 1) vminall = fminf(vminall, __shfl_xor(vminall, m));
    const float am = fmaxf(-vminall, rmall);  // == max(|min|,|max|) over my rows
    if (lane == 0) amax_s[wave] = am;
    __syncthreads();

    // ---------------- global barrier + scalar computation ----------------
    if (tid == 0) {
        const float amax = fmaxf(fmaxf(amax_s[0], amax_s[1]), fmaxf(amax_s[2], amax_s[3]));
        atomicMax(&g->amax_bits, __float_as_uint(amax));
        __threadfence();
        atomicAdd(&g->count, 1u);
        if (blockIdx.x == 0) {
            while (__hip_atomic_load(&g->count, __ATOMIC_ACQUIRE, __HIP_MEMORY_SCOPE_AGENT) < GRID) {
                __builtin_amdgcn_s_sleep(2);
            }
            const float sabs = __uint_as_float(
                __hip_atomic_load(&g->amax_bits, __ATOMIC_ACQUIRE, __HIP_MEMORY_SCOPE_AGENT));
            // sym_scale: max(|min|,|max|) == sabs; all f32 RN like the reference
            const float sf    = __fdiv_rn(fmaxf(sabs, 1e-8f), 32767.0f);
            const float x0i   = floorf(__fdiv_rn((float)(-0.6931), sf));
            const float sfsq  = __fmul_rn(sf, sf);
            const float b_int = floorf(__fdiv_rn((float)(0.96963238 / 0.35815147), sf));
            const float c_int = floorf(__fdiv_rn((float)(1.0 / 0.35815147), sfsq));
            const float exp_sf = __fdiv_rn(__fmul_rn((float)(0.35815147), sfsq), 1073741824.0f);
            // global exp_int max is exactly c_int*2^30 (row-max elem: r=0,q=0)
            const float emax   = __fmul_rn(c_int, 1073741824.0f);
            const float act_sf = __fdiv_rn(fmaxf(emax, 1e-8f), 32767.0f);
            const float  nsf = __fdiv_rn(exp_sf, act_sf);
            const double ns  = (double)nsf;
            int E;
            (void)frexp(ns, &E);             // e = floor(log2(ns)) + 1 == E exactly
            g->exp_sf_d   = (double)exp_sf;
            g->inv_exp_sf = 1.0 / (double)exp_sf;
            g->m_int      = rint(ldexp(ns, 31 - E));
            g->inv_pow    = ldexp(1.0, E - 31);
            g->sf         = sf;
            g->inv_sf     = __fdiv_rn(1.0f, sf);
            g->x0_int     = x0i;
            g->inv_x0     = __fdiv_rn(1.0f, x0i);
            g->b_int      = b_int;
            g->c_int      = c_int;
            g->thirty_x0  = __fmul_rn(30.0f, x0i);
            __threadfence();
            __hip_atomic_store(&g->flag, 1u, __ATOMIC_RELEASE, __HIP_MEMORY_SCOPE_AGENT);
        }
    }
    // every thread acquires the flag itself -> its own visibility of scalars
    while (__hip_atomic_load(&g->flag, __ATOMIC_ACQUIRE, __HIP_MEMORY_SCOPE_AGENT) == 0u) {
        __builtin_amdgcn_s_sleep(2);
    }
    __syncthreads();

    const float  sf     = g->sf,      inv_sf = g->inv_sf;
    const float  x0i    = g->x0_int,  inv_x0 = g->inv_x0;
    const float  b_int  = g->b_int,   c_int  = g->c_int, t30 = g->thirty_x0;
    const double esf    = g->exp_sf_d, iesf  = g->inv_exp_sf;
    const double mi     = g->m_int,    ipow  = g->inv_pow;

    // ---------------- phase 2: wave-per-row, no block barriers ----------------
    floatx4* o4 = (floatx4*)out;
    for (int k = iters - 1; k >= 0; --k) {   // reverse: L2/L3-MRU rows first
        const int rl = (k << 2) + wave;
        const size_t b4 = (size_t)(row0 + rl) * (ROW_S / 4) + lane;
        const float rm = rowmax_s[rl];
        // ximax = xi(row max of x): every x->xi step is monotone non-decreasing,
        // so this equals max over the row of xi bit-exactly.
        float ximax;
        {
            float t = rintf(div_rn(rm, sf, inv_sf));
            t = fminf(fmaxf(t, -32768.0f), 32767.0f);
            t = __fmul_rn(t, sf);
            ximax = div_rn(t, sf, inv_sf);
        }
        float4 v[8];
#pragma unroll
        for (int j = 0; j < 8; ++j) v[j] = x4[b4 + 64 * j];
        float e16[32];
        float ssum = 0.0f;
#pragma unroll
        for (int j = 0; j < 8; ++j) {
            const float xv[4] = {v[j].x, v[j].y, v[j].z, v[j].w};
#pragma unroll
            for (int c = 0; c < 4; ++c) {
                // QuantAct(16): clip(rint(x/sf)); dequant-requant (all RN, no FMA)
                float t = rintf(div_rn(xv[c], sf, inv_sf));
                t = fminf(fmaxf(t, -32768.0f), 32767.0f);
                t = __fmul_rn(t, sf);
                t = div_rn(t, sf, inv_sf);
                // int_exp
                const float xs = __fsub_rn(t, ximax);
                const float xm = fmaxf(xs, t30);
                const float qf = floorf(div_rn(xm, x0i, inv_x0));
                const float r  = __fsub_rn(xm, __fmul_rn(x0i, qf));
                // z = r*(r+b)+c — must NOT contract to FMA
                const float z  = __fadd_rn(__fmul_rn(r, __fadd_rn(r, b_int)), c_int);
                const int   qi = (int)qf;                          // in [0,30]
                const float p2 = __int_as_float((157 - qi) << 23); // exact 2^(30-qi)
                const float ei = fmaxf(floorf(__fmul_rn(z, p2)), 0.0f);
                // fixedpoint_mul in f64 (reference runs in double)
                const double zi = rint(ddiv_rn((double)ei, esf, iesf));
                double ov = rint(__dmul_rn(__dmul_rn(zi, mi), ipow));
                ov = fmin(fmax(ov, -32768.0), 32767.0);
                const float w = (float)ov;    // integer-valued, exact
                e16[4 * j + c] = w;
                ssum += w;    // non-neg ints, row sum < 2^24 -> order-free exact
            }
        }
#pragma unroll
        for (int m = 32; m > 0; m >>= 1) ssum += __shfl_xor(ssum, m);
        const float factor = floorf(__fdiv_rn(4294967296.0f, ssum));
#pragma unroll
        for (int j = 0; j < 8; ++j) {
            floatx4 w;
#pragma unroll
            for (int c = 0; c < 4; ++c) {
                // /2^24 == *2^-24 exact, then *2^-8 exact
                const float oi = floorf(__fmul_rn(__fmul_rn(e16[4 * j + c], factor),
                                                  5.9604644775390625e-8f));
                w[c] = __fmul_rn(oi, 0.00390625f);
            }
            __builtin_nontemporal_store(w, &o4[b4 + 64 * j]);
        }
    }
}

extern "C" void kernel_launch(void* const* d_in, const int* in_sizes, int n_in,
                              void* d_out, int out_size, void* d_ws, size_t ws_size,
                              hipStream_t stream) {
    const float* x = (const float*)d_in[0];
    float* out = (float*)d_out;
    const int n = in_sizes[0];          // 50331648
    const int rows = n / ROW_S;         // 24576

    Gsync* g = (Gsync*)d_ws;
    hipMemsetAsync(d_ws, 0, 64, stream);          // zero count/flag/amax_bits
    k_fused<<<GRID, TPB, 0, stream>>>(x, out, g, rows);
}

// Round 7
// 381.830 us; speedup vs baseline: 3.1926x; 3.1926x over previous
//
#include <hip/hip_runtime.h>
#include <math.h>

// I-BERT IntSoftmax, exact-numerics replication of the JAX reference.
// x: (1,12,2048,2048) f32; 24576 rows of S=2048.
// R7: two kernels. A: rowmax + global absmax via device atomicMax.
//     B: per-row quant-softmax; scalars derived redundantly per block from
//     amax_bits (bit-identical everywhere). No middle kernel, no persistent
//     barrier (R6 showed co-residency forces VGPR=36 -> scratch spill death).

#define ROW_S 2048
#define RPB 8                    // rows per block in pass 1
#define P1_BLOCKS (24576 / RPB)  // 3072

typedef float floatx4 __attribute__((ext_vector_type(4)));

// Markstein: with inv = RN(1/b), returns RN(a/b) bit-exactly.
__device__ __forceinline__ float div_rn(float a, float b, float inv) {
    const float q0 = __fmul_rn(a, inv);
    const float r  = __fmaf_rn(-b, q0, a);
    return __fmaf_rn(r, inv, q0);
}
__device__ __forceinline__ double ddiv_rn(double a, double b, double inv) {
    const double q0 = __dmul_rn(a, inv);
    const double r  = __fma_rn(-b, q0, a);
    return __fma_rn(r, inv, q0);
}

// Pass 1: per-row max of x + global abs-max (atomicMax on monotone uint bits).
__global__ __launch_bounds__(256) void k_pass1(const float* __restrict__ x,
                                               unsigned* __restrict__ amax_bits,
                                               float* __restrict__ rowmax) {
    const int t   = threadIdx.x;
    const int rib = t >> 5;          // row in block, 0..7
    const int lir = t & 31;          // lane in row
    const size_t base4 = ((size_t)blockIdx.x * RPB + rib) * (ROW_S / 4) + lir;
    const float4* x4 = (const float4*)x;

    float vmax = -INFINITY, amax = 0.0f;
#pragma unroll
    for (int k = 0; k < 16; ++k) {
        float4 v = x4[base4 + (size_t)k * 32];
        vmax = fmaxf(vmax, fmaxf(fmaxf(v.x, v.y), fmaxf(v.z, v.w)));
        amax = fmaxf(amax, fmaxf(fmaxf(fabsf(v.x), fabsf(v.y)),
                                 fmaxf(fabsf(v.z), fabsf(v.w))));
    }
    // row max across the 32 lanes of this row (xor<32 stays in-group)
#pragma unroll
    for (int m = 16; m > 0; m >>= 1) vmax = fmaxf(vmax, __shfl_xor(vmax, m));
    if (lir == 0) rowmax[blockIdx.x * RPB + rib] = vmax;
    // abs-max across full wave, then block, then one device atomic
#pragma unroll
    for (int m = 32; m > 0; m >>= 1) amax = fmaxf(amax, __shfl_xor(amax, m));
    __shared__ float sa[4];
    if ((t & 63) == 0) sa[t >> 6] = amax;
    __syncthreads();
    if (t == 0) {
        const float bm = fmaxf(fmaxf(sa[0], sa[1]), fmaxf(sa[2], sa[3]));
        atomicMax(amax_bits, __float_as_uint(bm));  // amax>=0: uint bits monotone
    }
}

__global__ __launch_bounds__(256) void k_row(const float* __restrict__ x,
                                             float* __restrict__ out,
                                             const unsigned* __restrict__ amax_bits,
                                             const float* __restrict__ rowmax) {
    const int tid = threadIdx.x;
    const size_t rowbase = (size_t)blockIdx.x * ROW_S;
    const float4* x4 = (const float4*)(x + rowbase);
    floatx4* o4 = (floatx4*)(out + rowbase);

    // issue global loads first; uniform scalar loads/compute overlap
    const float4 va = x4[tid];
    const float4 vb = x4[tid + 256];
    const float  rm = rowmax[blockIdx.x];
    const float  sabs = __uint_as_float(*amax_bits);

    // ---- derive scalars (uniform, deterministic -> identical in all blocks) ----
    // sym_scale: max(|min|,|max|) == max|x|; all f32 RN like the reference
    const float sf     = __fdiv_rn(fmaxf(sabs, 1e-8f), 32767.0f);
    const float inv_sf = __fdiv_rn(1.0f, sf);
    const float x0i    = floorf(__fdiv_rn((float)(-0.6931), sf));
    const float inv_x0 = __fdiv_rn(1.0f, x0i);
    const float sfsq   = __fmul_rn(sf, sf);
    const float b_int  = floorf(__fdiv_rn((float)(0.96963238 / 0.35815147), sf));
    const float c_int  = floorf(__fdiv_rn((float)(1.0 / 0.35815147), sfsq));
    const float exp_sf = __fdiv_rn(__fmul_rn((float)(0.35815147), sfsq), 1073741824.0f);
    const float t30    = __fmul_rn(30.0f, x0i);
    // global exp_int max is exactly c_int*2^30 (row-max elem: r=0,q=0 => z=c_int);
    // exp_int >= 0, so sym_scale(act) uses this max.
    const float emax   = __fmul_rn(c_int, 1073741824.0f);
    const float act_sf = __fdiv_rn(fmaxf(emax, 1e-8f), 32767.0f);
    // fixedpoint_mul scalar part (f64, per reference)
    const float  nsf = __fdiv_rn(exp_sf, act_sf);
    const double ns  = (double)nsf;
    int E;
    (void)frexp(ns, &E);                       // e = floor(log2(ns)) + 1 == E exactly
    const double mi   = rint(ldexp(ns, 31 - E));
    const double ipow = ldexp(1.0, E - 31);    // exact pow2
    const double esf  = (double)exp_sf;
    const double iesf = 1.0 / esf;             // RN f64 reciprocal (uniform)

    // ximax = xi(row max of x): every x->xi step is monotone non-decreasing,
    // so this equals max over the row of xi bit-exactly.
    float ximax;
    {
        float t = rintf(div_rn(rm, sf, inv_sf));
        t = fminf(fmaxf(t, -32768.0f), 32767.0f);
        t = __fmul_rn(t, sf);
        ximax = div_rn(t, sf, inv_sf);
    }

    float xv[8] = {va.x, va.y, va.z, va.w, vb.x, vb.y, vb.z, vb.w};

    float e16[8];
    float ssum = 0.0f;
#pragma unroll
    for (int j = 0; j < 8; ++j) {
        // QuantAct(16): x_int = clip(rint(x/sf)); xi = (x_int*sf)/sf (all RN, no FMA)
        float t = rintf(div_rn(xv[j], sf, inv_sf));
        t = fminf(fmaxf(t, -32768.0f), 32767.0f);
        t = __fmul_rn(t, sf);
        t = div_rn(t, sf, inv_sf);
        // int_exp
        const float xs = __fsub_rn(t, ximax);
        const float xm = fmaxf(xs, t30);
        const float qf = floorf(div_rn(xm, x0i, inv_x0));
        const float r  = __fsub_rn(xm, __fmul_rn(x0i, qf));
        // z = r*(r+b)+c — must NOT contract to FMA (XLA CPU doesn't)
        const float z  = __fadd_rn(__fmul_rn(r, __fadd_rn(r, b_int)), c_int);
        const int   qi = (int)qf;                          // qf in [0,30]
        const float p2 = __int_as_float((157 - qi) << 23); // exactly 2^(30-qi)
        const float ei = fmaxf(floorf(__fmul_rn(z, p2)), 0.0f);
        // fixedpoint_mul in f64 (reference runs in double)
        const double zi = rint(ddiv_rn((double)ei, esf, iesf));
        double ov = rint(__dmul_rn(__dmul_rn(zi, mi), ipow));
        ov = fmin(fmax(ov, -32768.0), 32767.0);
        const float v = (float)ov;   // integer-valued, exact
        e16[j] = v;
        ssum += v;   // non-negative ints, row sum < 2^24 -> order-free exact
    }

    // block sum: wave butterfly + 4-slot LDS, single barrier
    __shared__ float red[4];
    const int wave = tid >> 6, lane = tid & 63;
#pragma unroll
    for (int m = 32; m > 0; m >>= 1) ssum += __shfl_xor(ssum, m);
    if (lane == 0) red[wave] = ssum;
    __syncthreads();
    const float s = ((red[0] + red[1]) + (red[2] + red[3]));
    const float factor = floorf(__fdiv_rn(4294967296.0f, s));

    float ov[8];
#pragma unroll
    for (int j = 0; j < 8; ++j) {
        // /2^24 == *2^-24 exactly, then *2^-8 exact
        const float oi = floorf(__fmul_rn(__fmul_rn(e16[j], factor), 5.9604644775390625e-8f));
        ov[j] = __fmul_rn(oi, 0.00390625f);
    }
    floatx4 w0 = {ov[0], ov[1], ov[2], ov[3]};
    floatx4 w1 = {ov[4], ov[5], ov[6], ov[7]};
    __builtin_nontemporal_store(w0, &o4[tid]);
    __builtin_nontemporal_store(w1, &o4[tid + 256]);
}

extern "C" void kernel_launch(void* const* d_in, const int* in_sizes, int n_in,
                              void* d_out, int out_size, void* d_ws, size_t ws_size,
                              hipStream_t stream) {
    const float* x = (const float*)d_in[0];
    float* out = (float*)d_out;
    const int n = in_sizes[0];          // 50331648
    const int rows = n / ROW_S;         // 24576

    unsigned* amax_bits = (unsigned*)d_ws;              // needs zero init
    float* rowmax = (float*)((char*)d_ws + 256);

    hipMemsetAsync(d_ws, 0, 64, stream);   // amax_bits = 0 (poison 0xAA would stick in atomicMax)
    k_pass1<<<P1_BLOCKS, 256, 0, stream>>>(x, amax_bits, rowmax);
    k_row<<<rows, 256, 0, stream>>>(x, out, amax_bits, rowmax);
}

// Round 8
// 358.097 us; speedup vs baseline: 3.4042x; 1.0663x over previous
//
#include <hip/hip_runtime.h>
#include <math.h>

// I-BERT IntSoftmax, exact-numerics replication of the JAX reference.
// x: (1,12,2048,2048) f32; 24576 rows of S=2048.
// R8: R3 3-kernel structure + (a) pass1 emits per-row max (monotone-quant
//     hoist), (b) k_row processes 2 rows/block with interleaved independent
//     chains for 2x ILP on the f64 requant path, zero max-reduction barrier.
//     R7 lesson: scalars derived ONCE in a tiny kernel, never per-lane.

#define ROW_S 2048
#define RPB 8                    // rows per block in pass 1
#define P1_BLOCKS (24576 / RPB)  // 3072

typedef float floatx4 __attribute__((ext_vector_type(4)));

struct Scalars {
    double exp_sf_d;   // exp_sf (f64) — fixedpoint_mul divisor
    double inv_exp_sf; // RN(1/exp_sf_d)
    double m_int;      // 31-bit mantissa (f64)
    double inv_pow;    // 2^(e-31) exact
    float  sf;         // activation scale
    float  inv_sf;     // RN(1/sf)
    float  x0_int;     // floor(-0.6931/sf)
    float  inv_x0;     // RN(1/x0_int)
    float  b_int;      // floor(COEF1/sf)
    float  c_int;      // floor(COEF2/sf^2)
    float  thirty_x0;  // 30 * x0_int (exact)
    float  _pad;
};

// Markstein: with inv = RN(1/b), returns RN(a/b) bit-exactly.
__device__ __forceinline__ float div_rn(float a, float b, float inv) {
    const float q0 = __fmul_rn(a, inv);
    const float r  = __fmaf_rn(-b, q0, a);
    return __fmaf_rn(r, inv, q0);
}
__device__ __forceinline__ double ddiv_rn(double a, double b, double inv) {
    const double q0 = __dmul_rn(a, inv);
    const double r  = __fma_rn(-b, q0, a);
    return __fma_rn(r, inv, q0);
}

// Pass 1: per-row max of x + per-block abs-max partials. 8 rows/block, 32 lanes/row.
__global__ __launch_bounds__(256) void k_pass1(const float* __restrict__ x,
                                               float* __restrict__ pabs,
                                               float* __restrict__ rowmax) {
    const int t   = threadIdx.x;
    const int rib = t >> 5;          // row in block, 0..7
    const int lir = t & 31;          // lane in row
    const size_t base4 = ((size_t)blockIdx.x * RPB + rib) * (ROW_S / 4) + lir;
    const float4* x4 = (const float4*)x;

    float vmax = -INFINITY, amax = 0.0f;
#pragma unroll
    for (int k = 0; k < 16; ++k) {
        float4 v = x4[base4 + (size_t)k * 32];
        vmax = fmaxf(vmax, fmaxf(fmaxf(v.x, v.y), fmaxf(v.z, v.w)));
        amax = fmaxf(amax, fmaxf(fmaxf(fabsf(v.x), fabsf(v.y)),
                                 fmaxf(fabsf(v.z), fabsf(v.w))));
    }
    // row max across the 32 lanes of this row (xor<32 stays in-group)
#pragma unroll
    for (int m = 16; m > 0; m >>= 1) vmax = fmaxf(vmax, __shfl_xor(vmax, m));
    if (lir == 0) rowmax[blockIdx.x * RPB + rib] = vmax;
    // abs-max across full wave, then block
#pragma unroll
    for (int m = 32; m > 0; m >>= 1) amax = fmaxf(amax, __shfl_xor(amax, m));
    __shared__ float sa[4];
    if ((t & 63) == 0) sa[t >> 6] = amax;
    __syncthreads();
    if (t == 0) pabs[blockIdx.x] = fmaxf(fmaxf(sa[0], sa[1]), fmaxf(sa[2], sa[3]));
}

__global__ __launch_bounds__(256) void k_scalars(const float* __restrict__ pabs,
                                                 Scalars* __restrict__ sc) {
    const int tid = threadIdx.x;
    float amax = 0.0f;
    for (int i = tid; i < P1_BLOCKS; i += 256) amax = fmaxf(amax, pabs[i]);
#pragma unroll
    for (int m = 32; m > 0; m >>= 1) amax = fmaxf(amax, __shfl_xor(amax, m));
    __shared__ float sa[4];
    const int wave = tid >> 6, lane = tid & 63;
    if (lane == 0) sa[wave] = amax;
    __syncthreads();
    if (tid == 0) {
        const float sabs = fmaxf(fmaxf(sa[0], sa[1]), fmaxf(sa[2], sa[3]));
        // sym_scale: max(|min|,|max|) == max|x|; all f32 RN like the reference
        const float sf    = __fdiv_rn(fmaxf(sabs, 1e-8f), 32767.0f);
        const float x0i   = floorf(__fdiv_rn((float)(-0.6931), sf));
        const float sfsq  = __fmul_rn(sf, sf);
        const float b_int = floorf(__fdiv_rn((float)(0.96963238 / 0.35815147), sf));
        const float c_int = floorf(__fdiv_rn((float)(1.0 / 0.35815147), sfsq));
        const float exp_sf = __fdiv_rn(__fmul_rn((float)(0.35815147), sfsq), 1073741824.0f);
        // global exp_int max is exactly c_int*2^30 (row-max elem: r=0,q=0 => z=c_int)
        const float emax   = __fmul_rn(c_int, 1073741824.0f);
        const float act_sf = __fdiv_rn(fmaxf(emax, 1e-8f), 32767.0f);
        // fixedpoint_mul scalar part (f64, per reference)
        const float  nsf = __fdiv_rn(exp_sf, act_sf);
        const double ns  = (double)nsf;
        int E;
        (void)frexp(ns, &E);                 // e = floor(log2(ns)) + 1 == E exactly
        sc->exp_sf_d   = (double)exp_sf;
        sc->inv_exp_sf = 1.0 / (double)exp_sf;
        sc->m_int      = rint(ldexp(ns, 31 - E));
        sc->inv_pow    = ldexp(1.0, E - 31);
        sc->sf         = sf;
        sc->inv_sf     = __fdiv_rn(1.0f, sf);
        sc->x0_int     = x0i;
        sc->inv_x0     = __fdiv_rn(1.0f, x0i);
        sc->b_int      = b_int;
        sc->c_int      = c_int;
        sc->thirty_x0  = __fmul_rn(30.0f, x0i);
    }
}

// 2 rows per block, 16 elems/thread: two independent chains interleaved.
__global__ __launch_bounds__(256) void k_row2(const float* __restrict__ x,
                                              float* __restrict__ out,
                                              const Scalars* __restrict__ scp,
                                              const float* __restrict__ rowmax) {
    const int tid = threadIdx.x;
    const size_t r0 = (size_t)blockIdx.x * 2;
    const float4* x40 = (const float4*)(x + r0 * ROW_S);
    const float4* x41 = (const float4*)(x + (r0 + 1) * ROW_S);
    floatx4* o40 = (floatx4*)(out + r0 * ROW_S);
    floatx4* o41 = (floatx4*)(out + (r0 + 1) * ROW_S);

    // issue all 4 global loads first (MLP), uniform loads after
    const float4 va0 = x40[tid];
    const float4 vb0 = x40[tid + 256];
    const float4 va1 = x41[tid];
    const float4 vb1 = x41[tid + 256];
    const float  rm0 = rowmax[r0];
    const float  rm1 = rowmax[r0 + 1];

    const Scalars sc = *scp;
    const float sf = sc.sf, inv_sf = sc.inv_sf;
    const float x0i = sc.x0_int, inv_x0 = sc.inv_x0;
    const float b_int = sc.b_int, c_int = sc.c_int, t30 = sc.thirty_x0;
    const double esf = sc.exp_sf_d, iesf = sc.inv_exp_sf;
    const double mi = sc.m_int, ipow = sc.inv_pow;

    // ximax = xi(row max of x): every x->xi step is monotone non-decreasing,
    // so this equals max over the row of xi bit-exactly.
    float ximax0, ximax1;
    {
        float t = rintf(div_rn(rm0, sf, inv_sf));
        t = fminf(fmaxf(t, -32768.0f), 32767.0f);
        t = __fmul_rn(t, sf);
        ximax0 = div_rn(t, sf, inv_sf);
        float u = rintf(div_rn(rm1, sf, inv_sf));
        u = fminf(fmaxf(u, -32768.0f), 32767.0f);
        u = __fmul_rn(u, sf);
        ximax1 = div_rn(u, sf, inv_sf);
    }

    const float xv0[8] = {va0.x, va0.y, va0.z, va0.w, vb0.x, vb0.y, vb0.z, vb0.w};
    const float xv1[8] = {va1.x, va1.y, va1.z, va1.w, vb1.x, vb1.y, vb1.z, vb1.w};

    float e0[8], e1[8];
    float ssum0 = 0.0f, ssum1 = 0.0f;
#pragma unroll
    for (int j = 0; j < 8; ++j) {
        // ---- row 0, element j ----
        {
            float t = rintf(div_rn(xv0[j], sf, inv_sf));
            t = fminf(fmaxf(t, -32768.0f), 32767.0f);
            t = __fmul_rn(t, sf);
            t = div_rn(t, sf, inv_sf);
            const float xs = __fsub_rn(t, ximax0);
            const float xm = fmaxf(xs, t30);
            const float qf = floorf(div_rn(xm, x0i, inv_x0));
            const float r  = __fsub_rn(xm, __fmul_rn(x0i, qf));
            const float z  = __fadd_rn(__fmul_rn(r, __fadd_rn(r, b_int)), c_int);
            const int   qi = (int)qf;                          // in [0,30]
            const float p2 = __int_as_float((157 - qi) << 23); // exact 2^(30-qi)
            const float ei = fmaxf(floorf(__fmul_rn(z, p2)), 0.0f);
            const double zi = rint(ddiv_rn((double)ei, esf, iesf));
            double ov = rint(__dmul_rn(__dmul_rn(zi, mi), ipow));
            ov = fmin(fmax(ov, -32768.0), 32767.0);
            const float v = (float)ov;
            e0[j] = v;
            ssum0 += v;
        }
        // ---- row 1, element j (fully independent chain) ----
        {
            float t = rintf(div_rn(xv1[j], sf, inv_sf));
            t = fminf(fmaxf(t, -32768.0f), 32767.0f);
            t = __fmul_rn(t, sf);
            t = div_rn(t, sf, inv_sf);
            const float xs = __fsub_rn(t, ximax1);
            const float xm = fmaxf(xs, t30);
            const float qf = floorf(div_rn(xm, x0i, inv_x0));
            const float r  = __fsub_rn(xm, __fmul_rn(x0i, qf));
            const float z  = __fadd_rn(__fmul_rn(r, __fadd_rn(r, b_int)), c_int);
            const int   qi = (int)qf;
            const float p2 = __int_as_float((157 - qi) << 23);
            const float ei = fmaxf(floorf(__fmul_rn(z, p2)), 0.0f);
            const double zi = rint(ddiv_rn((double)ei, esf, iesf));
            double ov = rint(__dmul_rn(__dmul_rn(zi, mi), ipow));
            ov = fmin(fmax(ov, -32768.0), 32767.0);
            const float v = (float)ov;
            e1[j] = v;
            ssum1 += v;
        }
    }

    // both row sums: wave butterfly + LDS, single barrier
    __shared__ float red[8];
    const int wave = tid >> 6, lane = tid & 63;
#pragma unroll
    for (int m = 32; m > 0; m >>= 1) {
        ssum0 += __shfl_xor(ssum0, m);
        ssum1 += __shfl_xor(ssum1, m);
    }
    if (lane == 0) { red[wave] = ssum0; red[4 + wave] = ssum1; }
    __syncthreads();
    const float s0 = (red[0] + red[1]) + (red[2] + red[3]);
    const float s1 = (red[4] + red[5]) + (red[6] + red[7]);
    const float factor0 = floorf(__fdiv_rn(4294967296.0f, s0));
    const float factor1 = floorf(__fdiv_rn(4294967296.0f, s1));

    floatx4 w0, w1, w2, w3;
#pragma unroll
    for (int c = 0; c < 4; ++c) {
        // /2^24 == *2^-24 exact, then *2^-8 exact
        w0[c] = __fmul_rn(floorf(__fmul_rn(__fmul_rn(e0[c], factor0),
                                           5.9604644775390625e-8f)), 0.00390625f);
        w1[c] = __fmul_rn(floorf(__fmul_rn(__fmul_rn(e0[4 + c], factor0),
                                           5.9604644775390625e-8f)), 0.00390625f);
        w2[c] = __fmul_rn(floorf(__fmul_rn(__fmul_rn(e1[c], factor1),
                                           5.9604644775390625e-8f)), 0.00390625f);
        w3[c] = __fmul_rn(floorf(__fmul_rn(__fmul_rn(e1[4 + c], factor1),
                                           5.9604644775390625e-8f)), 0.00390625f);
    }
    __builtin_nontemporal_store(w0, &o40[tid]);
    __builtin_nontemporal_store(w1, &o40[tid + 256]);
    __builtin_nontemporal_store(w2, &o41[tid]);
    __builtin_nontemporal_store(w3, &o41[tid + 256]);
}

extern "C" void kernel_launch(void* const* d_in, const int* in_sizes, int n_in,
                              void* d_out, int out_size, void* d_ws, size_t ws_size,
                              hipStream_t stream) {
    const float* x = (const float*)d_in[0];
    float* out = (float*)d_out;
    const int n = in_sizes[0];          // 50331648
    const int rows = n / ROW_S;         // 24576

    Scalars* sc   = (Scalars*)d_ws;
    float* pabs   = (float*)((char*)d_ws + 256);
    float* rowmax = (float*)((char*)d_ws + 32768);

    k_pass1<<<P1_BLOCKS, 256, 0, stream>>>(x, pabs, rowmax);
    k_scalars<<<1, 256, 0, stream>>>(pabs, sc);
    k_row2<<<rows / 2, 256, 0, stream>>>(x, out, sc, rowmax);
}